// Round 5
// baseline (335.556 us; speedup 1.0000x reference)
//
#include <hip/hip_runtime.h>
#include <math.h>

#define D 128
#define HD 256
#define N_ENT 100000
#define NBATCH 64
#define NTOT (N_ENT + NBATCH)   // 100064
#define RCOUNT 500
#define E_BASE 400000
#define ETOT (E_BASE + N_ENT)   // 500000
#define NEG 0.2f
#define SCAN_NB 391             // 391*256 = 100096 (counts padded)
#define CPAD (SCAN_NB * 256)

#define WCAST_NB 64
#define ZERO_NB SCAN_NB
#define REL_NB (RCOUNT + 1)
#define PREP_NB (WCAST_NB + ZERO_NB + REL_NB)   // 956

#define GEMM_NB ((NTOT + 63) / 64)              // 1564
#define HIST_NB ((ETOT + 255) / 256)            // 1954

typedef __attribute__((ext_vector_type(8))) short bf16x8;
typedef __attribute__((ext_vector_type(8))) unsigned short u16x8;
typedef __attribute__((ext_vector_type(4))) float f32x4;

static __device__ __forceinline__ unsigned short f2bf(float f) {
  unsigned u = __builtin_bit_cast(unsigned, f);
  u += 0x7fffu + ((u >> 16) & 1u);   // RNE
  return (unsigned short)(u >> 16);
}
static __device__ __forceinline__ float bf2f(unsigned short h) {
  return __builtin_bit_cast(float, (unsigned)h << 16);
}

// ---------------- prep: Wbf cast | zero counts | e_rel + out_edge ----------------
__global__ __launch_bounds__(256) void k_prep(
    const float* __restrict__ W_l, const float* __restrict__ W_r,
    unsigned short* __restrict__ Wbf,
    const float* __restrict__ relations, const float* __restrict__ W_ea,
    const float* __restrict__ W_le, const float* __restrict__ b_le,
    unsigned short* __restrict__ e_rel, float* __restrict__ out_edge,
    int* __restrict__ counts) {
  __shared__ float relu_p[HD];
  int bx = blockIdx.x;
  int tid = threadIdx.x;
  if (bx < WCAST_NB) {
    int e4 = (bx * 256 + tid) * 4;
    int v = e4 >> 7;          // virtual row 0..511
    int k = e4 & 127;
    const float* src = (v < HD) ? (W_l + (size_t)v * D + k) : (W_r + (size_t)(v - HD) * D + k);
    float4 a = *(const float4*)src;
    *(ushort4*)(Wbf + (size_t)v * D + k) = make_ushort4(f2bf(a.x), f2bf(a.y), f2bf(a.z), f2bf(a.w));
    return;
  }
  if (bx < WCAST_NB + ZERO_NB) {
    counts[(bx - WCAST_NB) * 256 + tid] = 0;
    return;
  }
  int r = bx - (WCAST_NB + ZERO_NB);   // 0..500
  int j = tid;
  const float* w = W_ea + (size_t)j * D;
  float acc = 0.f;
  if (r < RCOUNT) {
    const float* rel = relations + (size_t)r * D;
    for (int k = 0; k < D; k += 4) {
      float4 a = *(const float4*)(rel + k);
      float4 b = *(const float4*)(w + k);
      acc += a.x * b.x + a.y * b.y + a.z * b.z + a.w * b.w;
    }
  } else {  // all-ones rel_feat row -> row sums of W_ea
    for (int k = 0; k < D; k += 4) {
      float4 b = *(const float4*)(w + k);
      acc += b.x + b.y + b.z + b.w;
    }
  }
  e_rel[(size_t)r * HD + j] = f2bf(acc);
  if (r < RCOUNT) {
    relu_p[j] = acc > 0.f ? acc : 0.f;
    __syncthreads();
    if (j < D) {
      const float* wl = W_le + (size_t)j * HD;
      float o = b_le[j];
      for (int k = 0; k < HD; k += 4) {
        float4 p4 = *(const float4*)(relu_p + k);
        float4 w4 = *(const float4*)(wl + k);
        o += p4.x * w4.x + p4.y * w4.y + p4.z * w4.z + p4.w * w4.w;
      }
      out_edge[(size_t)r * D + j] = o;
    }
  }
}

// ---------------- MFMA GEMM (64-row blocks, all 512 vcols) + fused edge histogram ----------------
#define LDA 136  // LDS row stride in ushort

__global__ __launch_bounds__(256) void k_gemm_mfma(
    const float* __restrict__ entities, const float* __restrict__ queries,
    const unsigned short* __restrict__ Wbf,
    const float* __restrict__ b_l, const float* __restrict__ b_r,
    unsigned short* __restrict__ x_l, unsigned short* __restrict__ x_r,
    const int* __restrict__ edge_index, int* __restrict__ counts) {
  __shared__ unsigned short As[64 * LDA];
  __shared__ unsigned short Cs[64 * LDA];
  int tid = threadIdx.x;
  if (blockIdx.x >= GEMM_NB) {   // histogram blocks
    int e = (blockIdx.x - GEMM_NB) * 256 + tid;
    if (e < ETOT) {
      int t = (e < E_BASE) ? edge_index[E_BASE + e] : (e - E_BASE);
      atomicAdd(counts + t, 1);
    }
    return;
  }
  int rb = blockIdx.x;          // 64-row tile

  // ---- stage A (fp32 -> bf16), once ----
  {
    int rr = tid >> 2;                 // 0..63
    int part = (tid & 3) * 32;
    int row = rb * 64 + rr;
    const float* sp;
    if (row < N_ENT) sp = entities + (size_t)row * D;
    else if (row < NTOT) sp = queries + (size_t)(row - N_ENT) * D;
    else sp = entities;  // dummy; stores guarded
#pragma unroll
    for (int k = 0; k < 32; k += 8) {
      float4 a0 = *(const float4*)(sp + part + k);
      float4 a1 = *(const float4*)(sp + part + k + 4);
      u16x8 p;
      p[0] = f2bf(a0.x); p[1] = f2bf(a0.y); p[2] = f2bf(a0.z); p[3] = f2bf(a0.w);
      p[4] = f2bf(a1.x); p[5] = f2bf(a1.y); p[6] = f2bf(a1.z); p[7] = f2bf(a1.w);
      *(u16x8*)(&As[rr * LDA + part + k]) = p;
    }
  }
  __syncthreads();

  int w = tid >> 6, lane = tid & 63;
  int wr = w >> 1, wc = w & 1;          // 2x2 wave grid per 128-col chunk
  int m = lane & 15, q8 = (lane >> 4) * 8;

  for (int ccv = 0; ccv < 4; ccv++) {   // virtual col chunks of 128 (0,1->x_l; 2,3->x_r)
    bool isL = ccv < 2;
    const float* bv = isL ? b_l : b_r;
    unsigned short* xdst = isL ? x_r : x_r;  // placeholder; fixed below
    xdst = isL ? x_l : x_r;
    int cbase = (ccv & 1) * 128;

    f32x4 acc[2][4];
#pragma unroll
    for (int i = 0; i < 2; i++)
#pragma unroll
      for (int j = 0; j < 4; j++) acc[i][j] = (f32x4){0.f, 0.f, 0.f, 0.f};

    const unsigned short* wbase = Wbf + (size_t)(ccv * 128 + wc * 64 + m) * D;
#pragma unroll
    for (int ks = 0; ks < 128; ks += 32) {
      bf16x8 af[2], bfr[4];
#pragma unroll
      for (int i = 0; i < 2; i++)
        af[i] = *(const bf16x8*)(&As[(wr * 32 + i * 16 + m) * LDA + ks + q8]);
#pragma unroll
      for (int j = 0; j < 4; j++)
        bfr[j] = *(const bf16x8*)(wbase + (size_t)j * 16 * D + ks + q8);
#pragma unroll
      for (int i = 0; i < 2; i++)
#pragma unroll
        for (int j = 0; j < 4; j++)
          acc[i][j] = __builtin_amdgcn_mfma_f32_16x16x32_bf16(af[i], bfr[j], acc[i][j], 0, 0, 0);
    }

    __syncthreads();  // prior chunk's Cs reads / stores complete
    // acc -> Cs (row-major, +bias, bf16). C layout: col=lane&15, row=(lane>>4)*4+reg
#pragma unroll
    for (int j = 0; j < 4; j++) {
      int col = wc * 64 + j * 16 + m;
      float bb = bv[cbase + col];
#pragma unroll
      for (int i = 0; i < 2; i++) {
        int row0 = wr * 32 + i * 16 + (lane >> 4) * 4;
#pragma unroll
        for (int r = 0; r < 4; r++)
          Cs[(row0 + r) * LDA + col] = f2bf(acc[i][j][r] + bb);
      }
    }
    __syncthreads();
    // coalesced global store: 64 rows x 128 cols bf16, 16B/thread-iter
#pragma unroll
    for (int it = 0; it < 4; it++) {
      int g = it * 256 + tid;
      int row = g >> 4, c8 = (g & 15) * 8;
      int grow = rb * 64 + row;
      if (grow < NTOT) {
        u16x8 v = *(const u16x8*)(&Cs[row * LDA + c8]);
        *(u16x8*)(xdst + (size_t)grow * HD + cbase + c8) = v;
      }
    }
  }
}

// ---------------- scan part a: per-block sums of counts ----------------
__global__ __launch_bounds__(256) void k_scan_a(const int* __restrict__ counts, int* __restrict__ bsum) {
  __shared__ int sd[256];
  int tid = threadIdx.x;
  sd[tid] = counts[blockIdx.x * 256 + tid];
  __syncthreads();
  for (int off = 128; off > 0; off >>= 1) {
    if (tid < off) sd[tid] += sd[tid + off];
    __syncthreads();
  }
  if (tid == 0) bsum[blockIdx.x] = sd[0];
}

// ---------------- scan part b: lookback over bsum + local scan -> offsets, cursor ----------------
__global__ __launch_bounds__(256) void k_scan_b(
    const int* __restrict__ counts, const int* __restrict__ bsum,
    int* __restrict__ offsets, int* __restrict__ cursor) {
  __shared__ int s[256];
  int b = blockIdx.x, tid = threadIdx.x;
  int part = 0;
  if (tid < b) part += bsum[tid];
  if (tid + 256 < b) part += bsum[tid + 256];
  s[tid] = part;
  __syncthreads();
  for (int off = 128; off > 0; off >>= 1) {
    if (tid < off) s[tid] += s[tid + off];
    __syncthreads();
  }
  int pre_sum = s[0];
  __syncthreads();
  int v = counts[b * 256 + tid];
  s[tid] = v;
  __syncthreads();
  for (int off = 1; off < 256; off <<= 1) {
    int y = (tid >= off) ? s[tid - off] : 0;
    __syncthreads();
    s[tid] += y;
    __syncthreads();
  }
  int excl = pre_sum + s[tid] - v;
  int i = b * 256 + tid;
  if (i <= N_ENT) offsets[i] = excl;   // i==N_ENT -> ETOT
  if (i < N_ENT) cursor[i] = excl;
}

__global__ void k_scatter(const int* __restrict__ edge_index, const int* __restrict__ relation_index,
                          const int* __restrict__ batch, int* __restrict__ cursor,
                          unsigned int* __restrict__ sorted) {
  int e = blockIdx.x * 256 + threadIdx.x;
  if (e >= ETOT) return;
  int s, t, r;
  if (e < E_BASE) {
    s = edge_index[e];
    t = edge_index[E_BASE + e];
    r = relation_index[e];
  } else {
    int i = e - E_BASE;
    s = N_ENT + batch[i];
    t = i;
    r = RCOUNT;
  }
  int pos = atomicAdd(cursor + t, 1);
  sorted[pos] = (unsigned)s | ((unsigned)r << 17);  // s<2^17, r<2^9
}

// ---------------- per-target aggregate: 4 edges/iter, 16 elems/lane ----------------
// lane = g*16 + sl (g=edge slot 0..3, sl=0..15); sl 0-7 head0, 8-15 head1.
__global__ __launch_bounds__(256) void k_edge(
    const unsigned short* __restrict__ x_l, const unsigned short* __restrict__ x_r,
    const unsigned short* __restrict__ e_rel, const int* __restrict__ offsets,
    const unsigned int* __restrict__ sorted, const float* __restrict__ att,
    const float* __restrict__ bias, float* __restrict__ out) {
  int wv = threadIdx.x >> 6;
  int lane = threadIdx.x & 63;
  int t = blockIdx.x * 4 + wv;  // grid is exactly N_ENT/4
  int g = lane >> 4;
  int sl = lane & 15;
  int elem = sl * 16;
  u16x8 xr0 = *(const u16x8*)(x_r + (size_t)t * HD + elem);
  u16x8 xr1 = *(const u16x8*)(x_r + (size_t)t * HD + elem + 8);
  float xr[16], at[16];
#pragma unroll
  for (int i = 0; i < 8; i++) { xr[i] = bf2f(xr0[i]); xr[8 + i] = bf2f(xr1[i]); }
#pragma unroll
  for (int i = 0; i < 16; i += 4) {
    float4 a = *(const float4*)(att + elem + i);
    at[i] = a.x; at[i + 1] = a.y; at[i + 2] = a.z; at[i + 3] = a.w;
  }
  int e0 = offsets[t], e1 = offsets[t + 1];
  float denom = 0.f;
  float acc[16];
#pragma unroll
  for (int i = 0; i < 16; i++) acc[i] = 0.f;

  for (int e = e0; e < e1; e += 4) {
    int ee = e + g;
    bool valid = ee < e1;
    unsigned sr = sorted[valid ? ee : e0];
    int s = sr & 0x1FFFF;
    int r = sr >> 17;
    const unsigned short* xlp = x_l + (size_t)s * HD + elem;
    const unsigned short* erp = e_rel + (size_t)r * HD + elem;
    u16x8 xl0 = *(const u16x8*)xlp;
    u16x8 xl1 = *(const u16x8*)(xlp + 8);
    u16x8 er0 = *(const u16x8*)erp;
    u16x8 er1 = *(const u16x8*)(erp + 8);
    float xl[16];
    float p = 0.f;
#pragma unroll
    for (int i = 0; i < 8; i++) {
      xl[i] = bf2f(xl0[i]);
      float z = xl[i] + xr[i] + bf2f(er0[i]);
      z = z > 0.f ? z : NEG * z;
      p += z * at[i];
    }
#pragma unroll
    for (int i = 0; i < 8; i++) {
      xl[8 + i] = bf2f(xl1[i]);
      float z = xl[8 + i] + xr[8 + i] + bf2f(er1[i]);
      z = z > 0.f ? z : NEG * z;
      p += z * at[8 + i];
    }
    // reduce over the 8-lane head subgroup (bits 0-2 of sl)
    p += __shfl_xor(p, 1, 64);
    p += __shfl_xor(p, 2, 64);
    p += __shfl_xor(p, 4, 64);
    float wgt = valid ? __expf(p) : 0.f;
    denom += wgt;
#pragma unroll
    for (int i = 0; i < 16; i++) acc[i] += wgt * xl[i];
  }
  // combine the 4 edge slots (lane bits 4,5)
  denom += __shfl_xor(denom, 16, 64);
  denom += __shfl_xor(denom, 32, 64);
#pragma unroll
  for (int i = 0; i < 16; i++) {
    acc[i] += __shfl_xor(acc[i], 16, 64);
    acc[i] += __shfl_xor(acc[i], 32, 64);
  }
  float inv = 1.f / (denom + 1e-16f);
  float o[16];
#pragma unroll
  for (int i = 0; i < 16; i++) o[i] = acc[i] * inv;
  // head mean: lane sl (head0, d=sl*16+i) pairs with lane sl^8 (head1, same d)
#pragma unroll
  for (int i = 0; i < 16; i++) o[i] += __shfl_xor(o[i], 8, 64);
  if (lane < 8) {
    int d = sl * 16;
#pragma unroll
    for (int i = 0; i < 16; i += 4) {
      float4 b4 = *(const float4*)(bias + d + i);
      *(float4*)(out + (size_t)t * D + d + i) =
          make_float4(o[i] * 0.5f + b4.x, o[i + 1] * 0.5f + b4.y,
                      o[i + 2] * 0.5f + b4.z, o[i + 3] * 0.5f + b4.w);
    }
  }
}

extern "C" void kernel_launch(void* const* d_in, const int* in_sizes, int n_in,
                              void* d_out, int out_size, void* d_ws, size_t ws_size,
                              hipStream_t stream) {
  const float* queries = (const float*)d_in[0];
  const float* entities = (const float*)d_in[1];
  const int* edge_index = (const int*)d_in[2];
  const float* relations = (const float*)d_in[3];
  const int* relation_index = (const int*)d_in[4];
  const int* batch = (const int*)d_in[5];
  const float* W_l = (const float*)d_in[6];
  const float* b_l = (const float*)d_in[7];
  const float* W_r = (const float*)d_in[8];
  const float* b_r = (const float*)d_in[9];
  const float* W_ea = (const float*)d_in[10];
  const float* att = (const float*)d_in[11];
  const float* bias = (const float*)d_in[12];
  const float* W_le = (const float*)d_in[13];
  const float* b_le = (const float*)d_in[14];

  float* out_node = (float*)d_out;
  float* out_edge = out_node + (size_t)N_ENT * D;

  char* base = (char*)d_ws;
  size_t off = 0;
  auto take = [&](size_t nbytes) -> void* {
    void* p = base + off;
    off += (nbytes + 255) & ~(size_t)255;
    return p;
  };
  unsigned short* x_l = (unsigned short*)take((size_t)NTOT * HD * sizeof(unsigned short)); // 51.2 MB
  unsigned short* x_r = (unsigned short*)take((size_t)NTOT * HD * sizeof(unsigned short)); // 51.2 MB
  unsigned short* e_rel = (unsigned short*)take((size_t)(RCOUNT + 1) * HD * sizeof(unsigned short));
  unsigned short* Wbf = (unsigned short*)take((size_t)512 * D * sizeof(unsigned short));   // 128 KB
  int* counts = (int*)take((size_t)CPAD * sizeof(int));                                    // padded to 100096
  int* offsets = (int*)take((size_t)(N_ENT + 1) * sizeof(int));
  int* cursor = (int*)take((size_t)N_ENT * sizeof(int));
  int* bsum = (int*)take(512 * sizeof(int));
  unsigned int* sorted = (unsigned int*)take((size_t)ETOT * sizeof(unsigned int));         // 2 MB

  k_prep<<<dim3(PREP_NB), dim3(256), 0, stream>>>(W_l, W_r, Wbf, relations, W_ea, W_le, b_le,
                                                  e_rel, out_edge, counts);
  k_gemm_mfma<<<dim3(GEMM_NB + HIST_NB), dim3(256), 0, stream>>>(entities, queries, Wbf, b_l, b_r,
                                                                 x_l, x_r, edge_index, counts);
  k_scan_a<<<dim3(SCAN_NB), dim3(256), 0, stream>>>(counts, bsum);
  k_scan_b<<<dim3(SCAN_NB), dim3(256), 0, stream>>>(counts, bsum, offsets, cursor);
  k_scatter<<<dim3(HIST_NB), dim3(256), 0, stream>>>(edge_index, relation_index, batch, cursor, sorted);
  k_edge<<<dim3(N_ENT / 4), dim3(256), 0, stream>>>(x_l, x_r, e_rel, offsets, sorted, att, bias, out_node);
}

// Round 6
// 306.014 us; speedup vs baseline: 1.0965x; 1.0965x over previous
//
#include <hip/hip_runtime.h>
#include <math.h>

#define D 128
#define HD 256
#define N_ENT 100000
#define NBATCH 64
#define NTOT (N_ENT + NBATCH)   // 100064
#define RCOUNT 500
#define E_BASE 400000
#define ETOT (E_BASE + N_ENT)   // 500000
#define NEG 0.2f
#define SCAN_NB 391             // 391*256 = 100096 (counts padded)
#define CPAD (SCAN_NB * 256)

#define WCAST_NB 64
#define ZERO_NB SCAN_NB
#define REL_NB (RCOUNT + 1)
#define PREP_NB (WCAST_NB + ZERO_NB + REL_NB)   // 956

#define GEMM_NB ((NTOT + 63) / 64)              // 1564
#define HIST_NB ((ETOT + 255) / 256)            // 1954

typedef __attribute__((ext_vector_type(8))) short bf16x8;
typedef __attribute__((ext_vector_type(8))) unsigned short u16x8;
typedef __attribute__((ext_vector_type(4))) float f32x4;

static __device__ __forceinline__ unsigned short f2bf(float f) {
  unsigned u = __builtin_bit_cast(unsigned, f);
  u += 0x7fffu + ((u >> 16) & 1u);   // RNE
  return (unsigned short)(u >> 16);
}
static __device__ __forceinline__ float bf2f(unsigned short h) {
  return __builtin_bit_cast(float, (unsigned)h << 16);
}

// ---------------- prep: Wbf cast | zero counts | e_rel + out_edge ----------------
__global__ __launch_bounds__(256) void k_prep(
    const float* __restrict__ W_l, const float* __restrict__ W_r,
    unsigned short* __restrict__ Wbf,
    const float* __restrict__ relations, const float* __restrict__ W_ea,
    const float* __restrict__ W_le, const float* __restrict__ b_le,
    unsigned short* __restrict__ e_rel, float* __restrict__ out_edge,
    int* __restrict__ counts) {
  __shared__ float relu_p[HD];
  int bx = blockIdx.x;
  int tid = threadIdx.x;
  if (bx < WCAST_NB) {
    int e4 = (bx * 256 + tid) * 4;
    int v = e4 >> 7;          // virtual row 0..511
    int k = e4 & 127;
    const float* src = (v < HD) ? (W_l + (size_t)v * D + k) : (W_r + (size_t)(v - HD) * D + k);
    float4 a = *(const float4*)src;
    *(ushort4*)(Wbf + (size_t)v * D + k) = make_ushort4(f2bf(a.x), f2bf(a.y), f2bf(a.z), f2bf(a.w));
    return;
  }
  if (bx < WCAST_NB + ZERO_NB) {
    counts[(bx - WCAST_NB) * 256 + tid] = 0;
    return;
  }
  int r = bx - (WCAST_NB + ZERO_NB);   // 0..500
  int j = tid;
  const float* w = W_ea + (size_t)j * D;
  float acc = 0.f;
  if (r < RCOUNT) {
    const float* rel = relations + (size_t)r * D;
    for (int k = 0; k < D; k += 4) {
      float4 a = *(const float4*)(rel + k);
      float4 b = *(const float4*)(w + k);
      acc += a.x * b.x + a.y * b.y + a.z * b.z + a.w * b.w;
    }
  } else {  // all-ones rel_feat row -> row sums of W_ea
    for (int k = 0; k < D; k += 4) {
      float4 b = *(const float4*)(w + k);
      acc += b.x + b.y + b.z + b.w;
    }
  }
  e_rel[(size_t)r * HD + j] = f2bf(acc);
  if (r < RCOUNT) {
    relu_p[j] = acc > 0.f ? acc : 0.f;
    __syncthreads();
    if (j < D) {
      const float* wl = W_le + (size_t)j * HD;
      float o = b_le[j];
      for (int k = 0; k < HD; k += 4) {
        float4 p4 = *(const float4*)(relu_p + k);
        float4 w4 = *(const float4*)(wl + k);
        o += p4.x * w4.x + p4.y * w4.y + p4.z * w4.z + p4.w * w4.w;
      }
      out_edge[(size_t)r * D + j] = o;
    }
  }
}

// ---------------- MFMA GEMM (64-row blocks, all 512 vcols) + fused edge histogram ----------------
#define LDA 136  // LDS row stride in ushort

__global__ __launch_bounds__(256) void k_gemm_mfma(
    const float* __restrict__ entities, const float* __restrict__ queries,
    const unsigned short* __restrict__ Wbf,
    const float* __restrict__ b_l, const float* __restrict__ b_r,
    unsigned short* __restrict__ x_l, unsigned short* __restrict__ x_r,
    const int* __restrict__ edge_index, int* __restrict__ counts) {
  __shared__ unsigned short As[64 * LDA];
  __shared__ unsigned short Cs[64 * LDA];
  int tid = threadIdx.x;
  if (blockIdx.x >= GEMM_NB) {   // histogram blocks
    int e = (blockIdx.x - GEMM_NB) * 256 + tid;
    if (e < ETOT) {
      int t = (e < E_BASE) ? edge_index[E_BASE + e] : (e - E_BASE);
      atomicAdd(counts + t, 1);
    }
    return;
  }
  int rb = blockIdx.x;          // 64-row tile

  // ---- stage A (fp32 -> bf16), once ----
  {
    int rr = tid >> 2;                 // 0..63
    int part = (tid & 3) * 32;
    int row = rb * 64 + rr;
    const float* sp;
    if (row < N_ENT) sp = entities + (size_t)row * D;
    else if (row < NTOT) sp = queries + (size_t)(row - N_ENT) * D;
    else sp = entities;  // dummy; stores guarded
#pragma unroll
    for (int k = 0; k < 32; k += 8) {
      float4 a0 = *(const float4*)(sp + part + k);
      float4 a1 = *(const float4*)(sp + part + k + 4);
      u16x8 p;
      p[0] = f2bf(a0.x); p[1] = f2bf(a0.y); p[2] = f2bf(a0.z); p[3] = f2bf(a0.w);
      p[4] = f2bf(a1.x); p[5] = f2bf(a1.y); p[6] = f2bf(a1.z); p[7] = f2bf(a1.w);
      *(u16x8*)(&As[rr * LDA + part + k]) = p;
    }
  }
  __syncthreads();

  int w = tid >> 6, lane = tid & 63;
  int wr = w >> 1, wc = w & 1;          // 2x2 wave grid per 128-col chunk
  int m = lane & 15, q8 = (lane >> 4) * 8;

  for (int ccv = 0; ccv < 4; ccv++) {   // virtual col chunks of 128 (0,1->x_l; 2,3->x_r)
    bool isL = ccv < 2;
    const float* bv = isL ? b_l : b_r;
    unsigned short* xdst = isL ? x_l : x_r;
    int cbase = (ccv & 1) * 128;

    f32x4 acc[2][4];
#pragma unroll
    for (int i = 0; i < 2; i++)
#pragma unroll
      for (int j = 0; j < 4; j++) acc[i][j] = (f32x4){0.f, 0.f, 0.f, 0.f};

    const unsigned short* wbase = Wbf + (size_t)(ccv * 128 + wc * 64 + m) * D;
#pragma unroll
    for (int ks = 0; ks < 128; ks += 32) {
      bf16x8 af[2], bfr[4];
#pragma unroll
      for (int i = 0; i < 2; i++)
        af[i] = *(const bf16x8*)(&As[(wr * 32 + i * 16 + m) * LDA + ks + q8]);
#pragma unroll
      for (int j = 0; j < 4; j++)
        bfr[j] = *(const bf16x8*)(wbase + (size_t)j * 16 * D + ks + q8);
#pragma unroll
      for (int i = 0; i < 2; i++)
#pragma unroll
        for (int j = 0; j < 4; j++)
          acc[i][j] = __builtin_amdgcn_mfma_f32_16x16x32_bf16(af[i], bfr[j], acc[i][j], 0, 0, 0);
    }

    __syncthreads();  // prior chunk's Cs reads / stores complete
    // acc -> Cs (row-major, +bias, bf16). C layout: col=lane&15, row=(lane>>4)*4+reg
#pragma unroll
    for (int j = 0; j < 4; j++) {
      int col = wc * 64 + j * 16 + m;
      float bb = bv[cbase + col];
#pragma unroll
      for (int i = 0; i < 2; i++) {
        int row0 = wr * 32 + i * 16 + (lane >> 4) * 4;
#pragma unroll
        for (int r = 0; r < 4; r++)
          Cs[(row0 + r) * LDA + col] = f2bf(acc[i][j][r] + bb);
      }
    }
    __syncthreads();
    // coalesced global store: 64 rows x 128 cols bf16, 16B/thread-iter
#pragma unroll
    for (int it = 0; it < 4; it++) {
      int g = it * 256 + tid;
      int row = g >> 4, c8 = (g & 15) * 8;
      int grow = rb * 64 + row;
      if (grow < NTOT) {
        u16x8 v = *(const u16x8*)(&Cs[row * LDA + c8]);
        *(u16x8*)(xdst + (size_t)grow * HD + cbase + c8) = v;
      }
    }
  }
}

// ---------------- scan part a: per-block sums of counts ----------------
__global__ __launch_bounds__(256) void k_scan_a(const int* __restrict__ counts, int* __restrict__ bsum) {
  __shared__ int sd[256];
  int tid = threadIdx.x;
  sd[tid] = counts[blockIdx.x * 256 + tid];
  __syncthreads();
  for (int off = 128; off > 0; off >>= 1) {
    if (tid < off) sd[tid] += sd[tid + off];
    __syncthreads();
  }
  if (tid == 0) bsum[blockIdx.x] = sd[0];
}

// ---------------- scan part b: lookback over bsum + local scan -> offsets, cursor ----------------
__global__ __launch_bounds__(256) void k_scan_b(
    const int* __restrict__ counts, const int* __restrict__ bsum,
    int* __restrict__ offsets, int* __restrict__ cursor) {
  __shared__ int s[256];
  int b = blockIdx.x, tid = threadIdx.x;
  int part = 0;
  if (tid < b) part += bsum[tid];
  if (tid + 256 < b) part += bsum[tid + 256];
  s[tid] = part;
  __syncthreads();
  for (int off = 128; off > 0; off >>= 1) {
    if (tid < off) s[tid] += s[tid + off];
    __syncthreads();
  }
  int pre_sum = s[0];
  __syncthreads();
  int v = counts[b * 256 + tid];
  s[tid] = v;
  __syncthreads();
  for (int off = 1; off < 256; off <<= 1) {
    int y = (tid >= off) ? s[tid - off] : 0;
    __syncthreads();
    s[tid] += y;
    __syncthreads();
  }
  int excl = pre_sum + s[tid] - v;
  int i = b * 256 + tid;
  if (i <= N_ENT) offsets[i] = excl;   // i==N_ENT -> ETOT
  if (i < N_ENT) cursor[i] = excl;
}

__global__ void k_scatter(const int* __restrict__ edge_index, const int* __restrict__ relation_index,
                          const int* __restrict__ batch, int* __restrict__ cursor,
                          unsigned int* __restrict__ sorted) {
  int e = blockIdx.x * 256 + threadIdx.x;
  if (e >= ETOT) return;
  int s, t, r;
  if (e < E_BASE) {
    s = edge_index[e];
    t = edge_index[E_BASE + e];
    r = relation_index[e];
  } else {
    int i = e - E_BASE;
    s = N_ENT + batch[i];
    t = i;
    r = RCOUNT;
  }
  int pos = atomicAdd(cursor + t, 1);
  sorted[pos] = (unsigned)s | ((unsigned)r << 17);  // s<2^17, r<2^9
}

// ---------------- per-target aggregate: 2 edges/wave-iter, 8 elems/lane ----------------
// lanes 0-31 edge e, lanes 32-63 edge e+1; within 32: sl 0-15 head0 (elems 0-127),
// sl 16-31 head1. Main loop peeled to 4 edges/iter with no validity logic (ILP x2).
__global__ __launch_bounds__(256) void k_edge(
    const unsigned short* __restrict__ x_l, const unsigned short* __restrict__ x_r,
    const unsigned short* __restrict__ e_rel, const int* __restrict__ offsets,
    const unsigned int* __restrict__ sorted, const float* __restrict__ att,
    const float* __restrict__ bias, float* __restrict__ out) {
  int wv = threadIdx.x >> 6;
  int lane = threadIdx.x & 63;
  int t = blockIdx.x * 4 + wv;  // grid is exactly N_ENT/4
  int half = lane >> 5;         // which edge of the pair
  int sl = lane & 31;
  int elem = sl * 8;            // head = sl>>4
  u16x8 xr8 = *(const u16x8*)(x_r + (size_t)t * HD + elem);
  float xr[8], at[8];
#pragma unroll
  for (int i = 0; i < 8; i++) xr[i] = bf2f(xr8[i]);
  float4 at0 = *(const float4*)(att + elem);
  float4 at1 = *(const float4*)(att + elem + 4);
  at[0] = at0.x; at[1] = at0.y; at[2] = at0.z; at[3] = at0.w;
  at[4] = at1.x; at[5] = at1.y; at[6] = at1.z; at[7] = at1.w;
  int e0 = offsets[t], e1 = offsets[t + 1];
  float denom = 0.f;
  float acc[8];
#pragma unroll
  for (int i = 0; i < 8; i++) acc[i] = 0.f;

  int e = e0;
  // ---- main: 4 valid edges per iter, two independent chains, no guards ----
  for (; e + 4 <= e1; e += 4) {
    unsigned srA = sorted[e + half];
    unsigned srB = sorted[e + 2 + half];
    const unsigned short* pA = x_l + (size_t)(srA & 0x1FFFF) * HD + elem;
    const unsigned short* qA = e_rel + (size_t)(srA >> 17) * HD + elem;
    const unsigned short* pB = x_l + (size_t)(srB & 0x1FFFF) * HD + elem;
    const unsigned short* qB = e_rel + (size_t)(srB >> 17) * HD + elem;
    u16x8 xlA = *(const u16x8*)pA;
    u16x8 erA = *(const u16x8*)qA;
    u16x8 xlB = *(const u16x8*)pB;
    u16x8 erB = *(const u16x8*)qB;
    float xa[8], xb[8];
    float pa = 0.f, pb = 0.f;
#pragma unroll
    for (int i = 0; i < 8; i++) {
      xa[i] = bf2f(xlA[i]);
      float za = xa[i] + xr[i] + bf2f(erA[i]);
      za = za > 0.f ? za : NEG * za;
      pa += za * at[i];
      xb[i] = bf2f(xlB[i]);
      float zb = xb[i] + xr[i] + bf2f(erB[i]);
      zb = zb > 0.f ? zb : NEG * zb;
      pb += zb * at[i];
    }
    pa += __shfl_xor(pa, 1, 64);  pb += __shfl_xor(pb, 1, 64);
    pa += __shfl_xor(pa, 2, 64);  pb += __shfl_xor(pb, 2, 64);
    pa += __shfl_xor(pa, 4, 64);  pb += __shfl_xor(pb, 4, 64);
    pa += __shfl_xor(pa, 8, 64);  pb += __shfl_xor(pb, 8, 64);
    float wa = __expf(pa);
    float wb = __expf(pb);
    denom += wa + wb;
#pragma unroll
    for (int i = 0; i < 8; i++) acc[i] += wa * xa[i] + wb * xb[i];
  }
  // ---- tail: guarded pairs (at most 2 iterations) ----
  for (; e < e1; e += 2) {
    int ee = e + half;
    bool valid = ee < e1;
    unsigned sr = sorted[valid ? ee : e0];
    int s = sr & 0x1FFFF;
    int r = sr >> 17;
    u16x8 xl8 = *(const u16x8*)(x_l + (size_t)s * HD + elem);
    u16x8 er8 = *(const u16x8*)(e_rel + (size_t)r * HD + elem);
    float xl[8];
    float p = 0.f;
#pragma unroll
    for (int i = 0; i < 8; i++) {
      xl[i] = bf2f(xl8[i]);
      float z = xl[i] + xr[i] + bf2f(er8[i]);
      z = z > 0.f ? z : NEG * z;
      p += z * at[i];
    }
    p += __shfl_xor(p, 1, 64);
    p += __shfl_xor(p, 2, 64);
    p += __shfl_xor(p, 4, 64);
    p += __shfl_xor(p, 8, 64);
    float wgt = valid ? __expf(p) : 0.f;
    denom += wgt;
#pragma unroll
    for (int i = 0; i < 8; i++) acc[i] += wgt * xl[i];
  }
  // combine the two edge-halves (same target, same head layout)
  denom += __shfl_xor(denom, 32, 64);
#pragma unroll
  for (int i = 0; i < 8; i++) acc[i] += __shfl_xor(acc[i], 32, 64);
  // normalize per head (denom is head-specific per 16-lane group)
  float inv = 1.f / (denom + 1e-16f);
  float o[8];
#pragma unroll
  for (int i = 0; i < 8; i++) o[i] = acc[i] * inv;
  // combine heads: lane sl (head0, d=8sl..) with lane sl^16 (head1, same d)
#pragma unroll
  for (int i = 0; i < 8; i++) o[i] += __shfl_xor(o[i], 16, 64);
  if (lane < 16) {
    int d = sl * 8;
    float4 b0 = *(const float4*)(bias + d);
    float4 b1 = *(const float4*)(bias + d + 4);
    *(float4*)(out + (size_t)t * D + d) =
        make_float4(o[0] * 0.5f + b0.x, o[1] * 0.5f + b0.y, o[2] * 0.5f + b0.z, o[3] * 0.5f + b0.w);
    *(float4*)(out + (size_t)t * D + d + 4) =
        make_float4(o[4] * 0.5f + b1.x, o[5] * 0.5f + b1.y, o[6] * 0.5f + b1.z, o[7] * 0.5f + b1.w);
  }
}

extern "C" void kernel_launch(void* const* d_in, const int* in_sizes, int n_in,
                              void* d_out, int out_size, void* d_ws, size_t ws_size,
                              hipStream_t stream) {
  const float* queries = (const float*)d_in[0];
  const float* entities = (const float*)d_in[1];
  const int* edge_index = (const int*)d_in[2];
  const float* relations = (const float*)d_in[3];
  const int* relation_index = (const int*)d_in[4];
  const int* batch = (const int*)d_in[5];
  const float* W_l = (const float*)d_in[6];
  const float* b_l = (const float*)d_in[7];
  const float* W_r = (const float*)d_in[8];
  const float* b_r = (const float*)d_in[9];
  const float* W_ea = (const float*)d_in[10];
  const float* att = (const float*)d_in[11];
  const float* bias = (const float*)d_in[12];
  const float* W_le = (const float*)d_in[13];
  const float* b_le = (const float*)d_in[14];

  float* out_node = (float*)d_out;
  float* out_edge = out_node + (size_t)N_ENT * D;

  char* base = (char*)d_ws;
  size_t off = 0;
  auto take = [&](size_t nbytes) -> void* {
    void* p = base + off;
    off += (nbytes + 255) & ~(size_t)255;
    return p;
  };
  unsigned short* x_l = (unsigned short*)take((size_t)NTOT * HD * sizeof(unsigned short)); // 51.2 MB
  unsigned short* x_r = (unsigned short*)take((size_t)NTOT * HD * sizeof(unsigned short)); // 51.2 MB
  unsigned short* e_rel = (unsigned short*)take((size_t)(RCOUNT + 1) * HD * sizeof(unsigned short));
  unsigned short* Wbf = (unsigned short*)take((size_t)512 * D * sizeof(unsigned short));   // 128 KB
  int* counts = (int*)take((size_t)CPAD * sizeof(int));                                    // padded to 100096
  int* offsets = (int*)take((size_t)(N_ENT + 1) * sizeof(int));
  int* cursor = (int*)take((size_t)N_ENT * sizeof(int));
  int* bsum = (int*)take(512 * sizeof(int));
  unsigned int* sorted = (unsigned int*)take((size_t)ETOT * sizeof(unsigned int));         // 2 MB

  k_prep<<<dim3(PREP_NB), dim3(256), 0, stream>>>(W_l, W_r, Wbf, relations, W_ea, W_le, b_le,
                                                  e_rel, out_edge, counts);
  k_gemm_mfma<<<dim3(GEMM_NB + HIST_NB), dim3(256), 0, stream>>>(entities, queries, Wbf, b_l, b_r,
                                                                 x_l, x_r, edge_index, counts);
  k_scan_a<<<dim3(SCAN_NB), dim3(256), 0, stream>>>(counts, bsum);
  k_scan_b<<<dim3(SCAN_NB), dim3(256), 0, stream>>>(counts, bsum, offsets, cursor);
  k_scatter<<<dim3(HIST_NB), dim3(256), 0, stream>>>(edge_index, relation_index, batch, cursor, sorted);
  k_edge<<<dim3(N_ENT / 4), dim3(256), 0, stream>>>(x_l, x_r, e_rel, offsets, sorted, att, bias, out_node);
}